// Round 1
// baseline (93.296 us; speedup 1.0000x reference)
//
#include <hip/hip_runtime.h>
#include <hip/hip_bf16.h>
#include <math.h>

// Problem: B=8, H=W=256, C=10 metric channels, all fp32.
// ws float layout: [0]=max(mass); [1..512]=block partial maxes;
//                  [1024 .. 1024+8*257*10) = per-batch LUT of T(mass).
#define GH 256
#define GW 256
#define NC 10
#define NKNOT 257

__device__ __forceinline__ float gelu_exact(float x) {
    return 0.5f * x * (1.0f + erff(x * 0.70710678118654752f));
}
__device__ __forceinline__ float softplus_f(float x) {
    if (x > 20.f) return x;
    return log1pf(expf(x));
}

// ---- Kernel 0: per-block max of mass (512 blocks x 256 threads, 4 elems each)
__global__ __launch_bounds__(256) void k_pmax(const float* __restrict__ mass,
                                              float* __restrict__ ws) {
    __shared__ float red[256];
    int tid = threadIdx.x;
    int idx = blockIdx.x * 256 + tid;
    float v = mass[idx];
    v = fmaxf(v, mass[idx + 131072]);
    v = fmaxf(v, mass[idx + 262144]);
    v = fmaxf(v, mass[idx + 393216]);
    red[tid] = v;
    __syncthreads();
    for (int s = 128; s > 0; s >>= 1) {
        if (tid < s) red[tid] = fmaxf(red[tid], red[tid + s]);
        __syncthreads();
    }
    if (tid == 0) ws[1 + blockIdx.x] = red[0];
}

// ---- Kernel 1: build LUT (blocks 0..8) + final max reduce (block 9)
__global__ __launch_bounds__(256) void k_lut(
        const float* __restrict__ vel,
        const float* __restrict__ e_w1, const float* __restrict__ e_b1,
        const float* __restrict__ e_w2, const float* __restrict__ e_b2,
        const float* __restrict__ m_w1, const float* __restrict__ m_b1,
        const float* __restrict__ m_w2, const float* __restrict__ m_b2,
        const float* __restrict__ s_w1, const float* __restrict__ s_b1,
        const float* __restrict__ s_w2, const float* __restrict__ s_b2,
        float* __restrict__ ws) {
    if (blockIdx.x == 9) {  // final reduce of 512 partials
        __shared__ float red[256];
        int tid = threadIdx.x;
        red[tid] = fmaxf(ws[1 + tid], ws[1 + 256 + tid]);
        __syncthreads();
        for (int s = 128; s > 0; s >>= 1) {
            if (tid < s) red[tid] = fmaxf(red[tid], red[tid + s]);
            __syncthreads();
        }
        if (tid == 0) ws[0] = red[0];
        return;
    }
    int g = blockIdx.x * 256 + threadIdx.x;
    if (g >= 8 * NKNOT) return;
    int b = g / NKNOT, knot = g % NKNOT;
    float m = (float)knot * (1.0f / 256.0f);
    float vx = vel[b * 3 + 0], vy = vel[b * 3 + 1], vz = vel[b * 3 + 2];
    float T[NC];
    // energy: 4->64->1, softplus
    float acc = e_b2[0];
    for (int j = 0; j < 64; j++) {
        float pre = m * e_w1[j] + vx * e_w1[64 + j] + vy * e_w1[128 + j]
                  + vz * e_w1[192 + j] + e_b1[j];
        acc += gelu_exact(pre) * e_w2[j];
    }
    T[0] = softplus_f(acc);
    // momentum: 4->64->3
    float a0 = m_b2[0], a1 = m_b2[1], a2 = m_b2[2];
    for (int j = 0; j < 64; j++) {
        float pre = m * m_w1[j] + vx * m_w1[64 + j] + vy * m_w1[128 + j]
                  + vz * m_w1[192 + j] + m_b1[j];
        float h = gelu_exact(pre);
        a0 += h * m_w2[j * 3 + 0];
        a1 += h * m_w2[j * 3 + 1];
        a2 += h * m_w2[j * 3 + 2];
    }
    T[1] = a0; T[2] = a1; T[3] = a2;
    // stress: 4->128->6
    float s[6];
    #pragma unroll
    for (int k = 0; k < 6; k++) s[k] = s_b2[k];
    for (int j = 0; j < 128; j++) {
        float pre = m * s_w1[j] + vx * s_w1[128 + j] + vy * s_w1[256 + j]
                  + vz * s_w1[384 + j] + s_b1[j];
        float h = gelu_exact(pre);
        #pragma unroll
        for (int k = 0; k < 6; k++) s[k] += h * s_w2[j * 6 + k];
    }
    #pragma unroll
    for (int k = 0; k < 6; k++) T[4 + k] = s[k];
    float* lut = ws + 1024 + (size_t)(b * NKNOT + knot) * NC;
    #pragma unroll
    for (int c = 0; c < NC; c++) lut[c] = T[c];
}

// ---- Kernel 2: fused metric compute + Poisson conv + clamps + 3x3 smooth
__global__ __launch_bounds__(256) void k_main(const float* __restrict__ mass,
                                              const float* __restrict__ minit,
                                              const float* __restrict__ solver,
                                              const float* __restrict__ ws,
                                              float* __restrict__ out) {
    const int b = blockIdx.z;
    const int tid = threadIdx.x;
    const int tx = tid & 15, ty = tid >> 4;
    const int tile_x = blockIdx.x * 16, tile_y = blockIdx.y * 16;

    __shared__ float s_mass[24][24];          // raw mass, halo 4
    __shared__ float s_lut[NKNOT * NC];       // this batch's LUT
    __shared__ float s_met[18][18][NC];       // pre-smooth metric, halo 1

    // load LUT
    const float* lutg = ws + 1024 + (size_t)b * NKNOT * NC;
    for (int i = tid; i < NKNOT * NC; i += 256) s_lut[i] = lutg[i];

    // load mass tile (raw values; zero outside image)
    const int gx0 = tile_x - 4, gy0 = tile_y - 4;
    const float* massb = mass + (size_t)b * GH * GW;
    for (int i = tid; i < 24 * 24; i += 256) {
        int ly = i / 24, lx = i % 24;
        int gy = gy0 + ly, gx = gx0 + lx;
        float v = 0.f;
        if ((unsigned)gy < GH && (unsigned)gx < GW) v = massb[gy * GW + gx];
        s_mass[ly][lx] = v;
    }

    // softmax(solver_params) — uniform across threads, cheap
    float p0 = solver[0], p1 = solver[1], p2 = solver[2];
    float pm = fmaxf(p0, fmaxf(p1, p2));
    float e0 = expf(p0 - pm), e1 = expf(p1 - pm), e2 = expf(p2 - pm);
    float inv = 1.f / (e0 + e1 + e2);
    float w0 = e0 * inv, w1 = e1 * inv, w2 = e2 * inv;
    float inv_max = 1.f / (ws[0] + 1e-8f);

    __syncthreads();

    // stage 2: pre-smooth metric over 18x18 region (origin at tile-1)
    for (int idx = tid; idx < 18 * 18; idx += 256) {
        int ly = idx / 18, lx = idx % 18;
        int gy = tile_y + ly - 1, gx = tile_x + lx - 1;
        if ((unsigned)gy >= GH || (unsigned)gx >= GW) {
            #pragma unroll
            for (int c = 0; c < NC; c++) s_met[ly][lx][c] = 0.f;  // zero pad
            continue;
        }
        float m = s_mass[ly + 3][lx + 3];
        // 7x7 Green's-function conv (kernel symmetric; center weight 0)
        float pot = 0.f;
        #pragma unroll
        for (int dy = 0; dy < 7; dy++) {
            #pragma unroll
            for (int dx = 0; dx < 7; dx++) {
                const int r2 = (dy - 3) * (dy - 3) + (dx - 3) * (dx - 3);
                if (r2 == 0) continue;
                const float wgt = -0.15915494309189535f * rsqrtf((float)r2);
                pot += wgt * s_mass[ly + dy][lx + dx];
            }
        }
        pot *= inv_max;  // conv is linear: normalize after
        // LUT lerp for T[0..9]
        float x = m * 256.f;
        int i0 = (int)x;
        i0 = i0 < 255 ? i0 : 255;
        float f = x - (float)i0;
        const float* mip = minit + ((size_t)(b * GH + gy) * GW + gx) * NC;
        float potterm = 2.f * w1 * pot;
        #pragma unroll
        for (int c = 0; c < NC; c++) {
            float t0 = s_lut[i0 * NC + c], t1 = s_lut[(i0 + 1) * NC + c];
            float T = fmaf(f, t1 - t0, t0);
            float v = mip[c] + w0 * (-25.132741228718345f * T);
            if (c == 4 || c == 7) v += potterm;
            if (c == 0) v = fminf(v, -0.1f);
            if (c == 4 || c == 7 || c == 9) v = fmaxf(v, 0.1f);
            s_met[ly][lx][c] = v;
        }
    }
    __syncthreads();

    // stage 3: 3x3 Gaussian (separable weights), select by w2>0.1, write out
    const int ly = ty + 1, lx = tx + 1;
    const int gy = tile_y + ty, gx = tile_x + tx;
    float* outp = out + ((size_t)(b * GH + gy) * GW + gx) * NC;
    const float g0 = 0.27406862f, g1 = 0.45186276f;
    const bool do_smooth = (w2 > 0.1f);
    #pragma unroll
    for (int c = 0; c < NC; c++) {
        float v;
        if (do_smooth) {
            float r0 = g0 * s_met[ly - 1][lx - 1][c] + g1 * s_met[ly - 1][lx][c] + g0 * s_met[ly - 1][lx + 1][c];
            float r1 = g0 * s_met[ly][lx - 1][c]     + g1 * s_met[ly][lx][c]     + g0 * s_met[ly][lx + 1][c];
            float r2 = g0 * s_met[ly + 1][lx - 1][c] + g1 * s_met[ly + 1][lx][c] + g0 * s_met[ly + 1][lx + 1][c];
            v = g0 * r0 + g1 * r1 + g0 * r2;
        } else {
            v = s_met[ly][lx][c];
        }
        outp[c] = v;
    }
}

extern "C" void kernel_launch(void* const* d_in, const int* in_sizes, int n_in,
                              void* d_out, int out_size, void* d_ws, size_t ws_size,
                              hipStream_t stream) {
    const float* mass   = (const float*)d_in[0];
    const float* vel    = (const float*)d_in[1];
    const float* minit  = (const float*)d_in[2];
    const float* e_w1   = (const float*)d_in[3];
    const float* e_b1   = (const float*)d_in[4];
    const float* e_w2   = (const float*)d_in[5];
    const float* e_b2   = (const float*)d_in[6];
    const float* m_w1   = (const float*)d_in[7];
    const float* m_b1   = (const float*)d_in[8];
    const float* m_w2   = (const float*)d_in[9];
    const float* m_b2   = (const float*)d_in[10];
    const float* s_w1   = (const float*)d_in[11];
    const float* s_b1   = (const float*)d_in[12];
    const float* s_w2   = (const float*)d_in[13];
    const float* s_b2   = (const float*)d_in[14];
    const float* solver = (const float*)d_in[15];
    float* ws  = (float*)d_ws;
    float* out = (float*)d_out;

    k_pmax<<<512, 256, 0, stream>>>(mass, ws);
    k_lut<<<10, 256, 0, stream>>>(vel, e_w1, e_b1, e_w2, e_b2,
                                  m_w1, m_b1, m_w2, m_b2,
                                  s_w1, s_b1, s_w2, s_b2, ws);
    dim3 grid(GW / 16, GH / 16, 8);
    k_main<<<grid, 256, 0, stream>>>(mass, minit, solver, ws, out);
}

// Round 2
// 44.372 us; speedup vs baseline: 2.1026x; 2.1026x over previous
//
#include <hip/hip_runtime.h>
#include <hip/hip_bf16.h>
#include <math.h>

// Problem: B=8, H=W=256, C=10 metric channels, all fp32.
// ws float layout: [0]=max(mass); [1..512]=block partial maxes;
//                  [1024 .. 1024+8*257*10) = per-batch LUT of T(mass).
#define GH 256
#define GW 256
#define NC 10
#define NKNOT 257

__device__ __forceinline__ float gelu_exact(float x) {
    return 0.5f * x * (1.0f + erff(x * 0.70710678118654752f));
}
__device__ __forceinline__ float softplus_f(float x) {
    if (x > 20.f) return x;
    return log1pf(expf(x));
}

// ---- Kernel 0: per-block max of mass (512 blocks x 256 threads, 4 elems each)
__global__ __launch_bounds__(256) void k_pmax(const float* __restrict__ mass,
                                              float* __restrict__ ws) {
    __shared__ float red[256];
    int tid = threadIdx.x;
    int idx = blockIdx.x * 256 + tid;
    float v = mass[idx];
    v = fmaxf(v, mass[idx + 131072]);
    v = fmaxf(v, mass[idx + 262144]);
    v = fmaxf(v, mass[idx + 393216]);
    red[tid] = v;
    __syncthreads();
    for (int s = 128; s > 0; s >>= 1) {
        if (tid < s) red[tid] = fmaxf(red[tid], red[tid + s]);
        __syncthreads();
    }
    if (tid == 0) ws[1 + blockIdx.x] = red[0];
}

// ---- Kernel 1: build LUT — one WAVE per (batch,knot), lanes split hidden dim.
// blocks 0..513 (4 waves each = 2056 waves); block 514 does final max reduce.
__global__ __launch_bounds__(256) void k_lut(
        const float* __restrict__ vel,
        const float* __restrict__ e_w1, const float* __restrict__ e_b1,
        const float* __restrict__ e_w2, const float* __restrict__ e_b2,
        const float* __restrict__ m_w1, const float* __restrict__ m_b1,
        const float* __restrict__ m_w2, const float* __restrict__ m_b2,
        const float* __restrict__ s_w1, const float* __restrict__ s_b1,
        const float* __restrict__ s_w2, const float* __restrict__ s_b2,
        float* __restrict__ ws) {
    if (blockIdx.x == 514) {  // final reduce of 512 partials
        __shared__ float red[256];
        int tid = threadIdx.x;
        red[tid] = fmaxf(ws[1 + tid], ws[1 + 256 + tid]);
        __syncthreads();
        for (int s = 128; s > 0; s >>= 1) {
            if (tid < s) red[tid] = fmaxf(red[tid], red[tid + s]);
            __syncthreads();
        }
        if (tid == 0) ws[0] = red[0];
        return;
    }
    const int wave = blockIdx.x * 4 + (threadIdx.x >> 6);
    const int lane = threadIdx.x & 63;
    if (wave >= 8 * NKNOT) return;
    const int b = wave / NKNOT, knot = wave % NKNOT;
    const float m = (float)knot * (1.0f / 256.0f);
    const float vx = vel[b * 3 + 0], vy = vel[b * 3 + 1], vz = vel[b * 3 + 2];

    float acc[10];
    // energy hidden unit `lane`
    {
        float pre = m * e_w1[lane] + vx * e_w1[64 + lane] + vy * e_w1[128 + lane]
                  + vz * e_w1[192 + lane] + e_b1[lane];
        acc[0] = gelu_exact(pre) * e_w2[lane];
    }
    // momentum hidden unit `lane`
    {
        float pre = m * m_w1[lane] + vx * m_w1[64 + lane] + vy * m_w1[128 + lane]
                  + vz * m_w1[192 + lane] + m_b1[lane];
        float h = gelu_exact(pre);
        acc[1] = h * m_w2[lane * 3 + 0];
        acc[2] = h * m_w2[lane * 3 + 1];
        acc[3] = h * m_w2[lane * 3 + 2];
    }
    // stress hidden units `lane` and `lane+64`
    {
        float pre0 = m * s_w1[lane] + vx * s_w1[128 + lane] + vy * s_w1[256 + lane]
                   + vz * s_w1[384 + lane] + s_b1[lane];
        float pre1 = m * s_w1[64 + lane] + vx * s_w1[192 + lane] + vy * s_w1[320 + lane]
                   + vz * s_w1[448 + lane] + s_b1[64 + lane];
        float h0 = gelu_exact(pre0), h1 = gelu_exact(pre1);
        #pragma unroll
        for (int k = 0; k < 6; k++)
            acc[4 + k] = h0 * s_w2[lane * 6 + k] + h1 * s_w2[(lane + 64) * 6 + k];
    }
    // butterfly reduce all 10 across the 64-lane wave
    #pragma unroll
    for (int c = 0; c < 10; c++) {
        float v = acc[c];
        #pragma unroll
        for (int off = 32; off > 0; off >>= 1)
            v += __shfl_xor(v, off, 64);
        acc[c] = v;
    }
    if (lane == 0) {
        float* lut = ws + 1024 + (size_t)(b * NKNOT + knot) * NC;
        lut[0] = softplus_f(acc[0] + e_b2[0]);
        lut[1] = acc[1] + m_b2[0];
        lut[2] = acc[2] + m_b2[1];
        lut[3] = acc[3] + m_b2[2];
        #pragma unroll
        for (int k = 0; k < 6; k++) lut[4 + k] = acc[4 + k] + s_b2[k];
    }
}

// ---- Kernel 2: fused metric compute + Poisson conv + clamps + 3x3 smooth
__global__ __launch_bounds__(256) void k_main(const float* __restrict__ mass,
                                              const float* __restrict__ minit,
                                              const float* __restrict__ solver,
                                              const float* __restrict__ ws,
                                              float* __restrict__ out) {
    const int b = blockIdx.z;
    const int tid = threadIdx.x;
    const int tx = tid & 15, ty = tid >> 4;
    const int tile_x = blockIdx.x * 16, tile_y = blockIdx.y * 16;

    __shared__ float s_mass[24][24];          // raw mass, halo 4
    __shared__ float s_lut[NKNOT * NC];       // this batch's LUT
    __shared__ float s_met[18][18][NC];       // pre-smooth metric, halo 1

    // load LUT
    const float* lutg = ws + 1024 + (size_t)b * NKNOT * NC;
    for (int i = tid; i < NKNOT * NC; i += 256) s_lut[i] = lutg[i];

    // load mass tile (raw values; zero outside image)
    const int gx0 = tile_x - 4, gy0 = tile_y - 4;
    const float* massb = mass + (size_t)b * GH * GW;
    for (int i = tid; i < 24 * 24; i += 256) {
        int ly = i / 24, lx = i % 24;
        int gy = gy0 + ly, gx = gx0 + lx;
        float v = 0.f;
        if ((unsigned)gy < GH && (unsigned)gx < GW) v = massb[gy * GW + gx];
        s_mass[ly][lx] = v;
    }

    // softmax(solver_params) — uniform across threads, cheap
    float p0 = solver[0], p1 = solver[1], p2 = solver[2];
    float pm = fmaxf(p0, fmaxf(p1, p2));
    float e0 = expf(p0 - pm), e1 = expf(p1 - pm), e2 = expf(p2 - pm);
    float inv = 1.f / (e0 + e1 + e2);
    float w0 = e0 * inv, w1 = e1 * inv, w2 = e2 * inv;
    float inv_max = 1.f / (ws[0] + 1e-8f);

    __syncthreads();

    // stage 2: pre-smooth metric over 18x18 region (origin at tile-1)
    for (int idx = tid; idx < 18 * 18; idx += 256) {
        int ly = idx / 18, lx = idx % 18;
        int gy = tile_y + ly - 1, gx = tile_x + lx - 1;
        if ((unsigned)gy >= GH || (unsigned)gx >= GW) {
            #pragma unroll
            for (int c = 0; c < NC; c++) s_met[ly][lx][c] = 0.f;  // zero pad
            continue;
        }
        float m = s_mass[ly + 3][lx + 3];
        // 7x7 Green's-function conv (kernel symmetric; center weight 0)
        float pot = 0.f;
        #pragma unroll
        for (int dy = 0; dy < 7; dy++) {
            #pragma unroll
            for (int dx = 0; dx < 7; dx++) {
                const int r2 = (dy - 3) * (dy - 3) + (dx - 3) * (dx - 3);
                if (r2 == 0) continue;
                const float wgt = -0.15915494309189535f * rsqrtf((float)r2);
                pot += wgt * s_mass[ly + dy][lx + dx];
            }
        }
        pot *= inv_max;  // conv is linear: normalize after
        // LUT lerp for T[0..9]
        float x = m * 256.f;
        int i0 = (int)x;
        i0 = i0 < 255 ? i0 : 255;
        float f = x - (float)i0;
        const float* mip = minit + ((size_t)(b * GH + gy) * GW + gx) * NC;
        float potterm = 2.f * w1 * pot;
        #pragma unroll
        for (int c = 0; c < NC; c++) {
            float t0 = s_lut[i0 * NC + c], t1 = s_lut[(i0 + 1) * NC + c];
            float T = fmaf(f, t1 - t0, t0);
            float v = mip[c] + w0 * (-25.132741228718345f * T);
            if (c == 4 || c == 7) v += potterm;
            if (c == 0) v = fminf(v, -0.1f);
            if (c == 4 || c == 7 || c == 9) v = fmaxf(v, 0.1f);
            s_met[ly][lx][c] = v;
        }
    }
    __syncthreads();

    // stage 3: 3x3 Gaussian (separable weights), select by w2>0.1, write out
    const int ly = ty + 1, lx = tx + 1;
    const int gy = tile_y + ty, gx = tile_x + tx;
    float* outp = out + ((size_t)(b * GH + gy) * GW + gx) * NC;
    const float g0 = 0.27406862f, g1 = 0.45186276f;
    const bool do_smooth = (w2 > 0.1f);
    #pragma unroll
    for (int c = 0; c < NC; c++) {
        float v;
        if (do_smooth) {
            float r0 = g0 * s_met[ly - 1][lx - 1][c] + g1 * s_met[ly - 1][lx][c] + g0 * s_met[ly - 1][lx + 1][c];
            float r1 = g0 * s_met[ly][lx - 1][c]     + g1 * s_met[ly][lx][c]     + g0 * s_met[ly][lx + 1][c];
            float r2 = g0 * s_met[ly + 1][lx - 1][c] + g1 * s_met[ly + 1][lx][c] + g0 * s_met[ly + 1][lx + 1][c];
            v = g0 * r0 + g1 * r1 + g0 * r2;
        } else {
            v = s_met[ly][lx][c];
        }
        outp[c] = v;
    }
}

extern "C" void kernel_launch(void* const* d_in, const int* in_sizes, int n_in,
                              void* d_out, int out_size, void* d_ws, size_t ws_size,
                              hipStream_t stream) {
    const float* mass   = (const float*)d_in[0];
    const float* vel    = (const float*)d_in[1];
    const float* minit  = (const float*)d_in[2];
    const float* e_w1   = (const float*)d_in[3];
    const float* e_b1   = (const float*)d_in[4];
    const float* e_w2   = (const float*)d_in[5];
    const float* e_b2   = (const float*)d_in[6];
    const float* m_w1   = (const float*)d_in[7];
    const float* m_b1   = (const float*)d_in[8];
    const float* m_w2   = (const float*)d_in[9];
    const float* m_b2   = (const float*)d_in[10];
    const float* s_w1   = (const float*)d_in[11];
    const float* s_b1   = (const float*)d_in[12];
    const float* s_w2   = (const float*)d_in[13];
    const float* s_b2   = (const float*)d_in[14];
    const float* solver = (const float*)d_in[15];
    float* ws  = (float*)d_ws;
    float* out = (float*)d_out;

    k_pmax<<<512, 256, 0, stream>>>(mass, ws);
    k_lut<<<515, 256, 0, stream>>>(vel, e_w1, e_b1, e_w2, e_b2,
                                   m_w1, m_b1, m_w2, m_b2,
                                   s_w1, s_b1, s_w2, s_b2, ws);
    dim3 grid(GW / 16, GH / 16, 8);
    k_main<<<grid, 256, 0, stream>>>(mass, minit, solver, ws, out);
}

// Round 3
// 28.947 us; speedup vs baseline: 3.2230x; 1.5329x over previous
//
#include <hip/hip_runtime.h>
#include <hip/hip_bf16.h>
#include <math.h>

// Problem: B=8, H=W=256, C=10 metric channels, all fp32.
// ws float layout: [0..255] = per-block partial maxes of mass;
//                  [1024 .. 1024+8*257*10) = per-batch LUT of T(mass).
#define GH 256
#define GW 256
#define NC 10
#define NKNOT 257

__device__ __forceinline__ float gelu_exact(float x) {
    return 0.5f * x * (1.0f + erff(x * 0.70710678118654752f));
}
__device__ __forceinline__ float softplus_f(float x) {
    if (x > 20.f) return x;
    return log1pf(expf(x));
}

// ---- Kernel 1: blocks 0..513 build LUT (one wave per (batch,knot));
//      blocks 514..769 compute partial max of mass (float4 loads).
__global__ __launch_bounds__(256) void k_pre(
        const float* __restrict__ mass,
        const float* __restrict__ vel,
        const float* __restrict__ e_w1, const float* __restrict__ e_b1,
        const float* __restrict__ e_w2, const float* __restrict__ e_b2,
        const float* __restrict__ m_w1, const float* __restrict__ m_b1,
        const float* __restrict__ m_w2, const float* __restrict__ m_b2,
        const float* __restrict__ s_w1, const float* __restrict__ s_b1,
        const float* __restrict__ s_w2, const float* __restrict__ s_b2,
        float* __restrict__ ws) {
    const int tid = threadIdx.x;
    if (blockIdx.x >= 514) {  // ---- partial max over mass
        const int pb = blockIdx.x - 514;           // 0..255
        const float4* mass4 = (const float4*)mass; // 131072 float4 total
        int base = pb * 512 + tid;                 // 512 float4 per block
        float4 a = mass4[base];
        float4 c = mass4[base + 256];
        float v = fmaxf(fmaxf(fmaxf(a.x, a.y), fmaxf(a.z, a.w)),
                        fmaxf(fmaxf(c.x, c.y), fmaxf(c.z, c.w)));
        #pragma unroll
        for (int off = 32; off > 0; off >>= 1)
            v = fmaxf(v, __shfl_xor(v, off, 64));
        __shared__ float sred[4];
        if ((tid & 63) == 0) sred[tid >> 6] = v;
        __syncthreads();
        if (tid == 0)
            ws[pb] = fmaxf(fmaxf(sred[0], sred[1]), fmaxf(sred[2], sred[3]));
        return;
    }
    // ---- LUT build: wave-parallel over hidden dim
    const int wave = blockIdx.x * 4 + (tid >> 6);   // 0..2055 == 8*257-1
    const int lane = tid & 63;
    const int b = wave / NKNOT, knot = wave % NKNOT;
    const float m = (float)knot * (1.0f / 256.0f);
    const float vx = vel[b * 3 + 0], vy = vel[b * 3 + 1], vz = vel[b * 3 + 2];

    float acc[10];
    {   // energy hidden unit `lane`
        float pre = m * e_w1[lane] + vx * e_w1[64 + lane] + vy * e_w1[128 + lane]
                  + vz * e_w1[192 + lane] + e_b1[lane];
        acc[0] = gelu_exact(pre) * e_w2[lane];
    }
    {   // momentum hidden unit `lane`
        float pre = m * m_w1[lane] + vx * m_w1[64 + lane] + vy * m_w1[128 + lane]
                  + vz * m_w1[192 + lane] + m_b1[lane];
        float h = gelu_exact(pre);
        acc[1] = h * m_w2[lane * 3 + 0];
        acc[2] = h * m_w2[lane * 3 + 1];
        acc[3] = h * m_w2[lane * 3 + 2];
    }
    {   // stress hidden units `lane`, `lane+64`
        float pre0 = m * s_w1[lane] + vx * s_w1[128 + lane] + vy * s_w1[256 + lane]
                   + vz * s_w1[384 + lane] + s_b1[lane];
        float pre1 = m * s_w1[64 + lane] + vx * s_w1[192 + lane] + vy * s_w1[320 + lane]
                   + vz * s_w1[448 + lane] + s_b1[64 + lane];
        float h0 = gelu_exact(pre0), h1 = gelu_exact(pre1);
        #pragma unroll
        for (int k = 0; k < 6; k++)
            acc[4 + k] = h0 * s_w2[lane * 6 + k] + h1 * s_w2[(lane + 64) * 6 + k];
    }
    #pragma unroll
    for (int c = 0; c < 10; c++) {
        float v = acc[c];
        #pragma unroll
        for (int off = 32; off > 0; off >>= 1)
            v += __shfl_xor(v, off, 64);
        acc[c] = v;
    }
    if (lane == 0) {
        float* lut = ws + 1024 + (size_t)(b * NKNOT + knot) * NC;
        lut[0] = softplus_f(acc[0] + e_b2[0]);
        lut[1] = acc[1] + m_b2[0];
        lut[2] = acc[2] + m_b2[1];
        lut[3] = acc[3] + m_b2[2];
        #pragma unroll
        for (int k = 0; k < 6; k++) lut[4 + k] = acc[4 + k] + s_b2[k];
    }
}

// ---- Kernel 2: fused max-finalize + metric + Poisson conv + clamps + smooth.
// float2 channel-pair pipeline throughout.
__global__ __launch_bounds__(256) void k_main(const float* __restrict__ mass,
                                              const float* __restrict__ minit,
                                              const float* __restrict__ solver,
                                              const float* __restrict__ ws,
                                              float* __restrict__ out) {
    const int b = blockIdx.z;
    const int tid = threadIdx.x;
    const int tx = tid & 15, ty = tid >> 4;
    const int tile_x = blockIdx.x * 16, tile_y = blockIdx.y * 16;

    __shared__ float  s_mass[24][24];         // raw mass, halo 4
    __shared__ float2 s_lut2[NKNOT * 5];      // this batch's LUT (channel pairs)
    __shared__ float2 s_met2[5][18][18];      // pre-smooth metric, halo 1
    __shared__ float  s_wmax[4];

    // finalize global max (256 partials, 1/thread) — merged into load phase
    {
        float v = ws[tid];
        #pragma unroll
        for (int off = 32; off > 0; off >>= 1)
            v = fmaxf(v, __shfl_xor(v, off, 64));
        if ((tid & 63) == 0) s_wmax[tid >> 6] = v;
    }
    // load LUT as float2 (2570 floats = 1285 float2)
    const float2* lutg2 = (const float2*)(ws + 1024 + (size_t)b * NKNOT * NC);
    for (int i = tid; i < NKNOT * 5; i += 256) s_lut2[i] = lutg2[i];

    // load mass tile (raw; zero outside image)
    const int gx0 = tile_x - 4, gy0 = tile_y - 4;
    const float* massb = mass + (size_t)b * GH * GW;
    for (int i = tid; i < 24 * 24; i += 256) {
        int ly = i / 24, lx = i % 24;
        int gy = gy0 + ly, gx = gx0 + lx;
        float v = 0.f;
        if ((unsigned)gy < GH && (unsigned)gx < GW) v = massb[gy * GW + gx];
        s_mass[ly][lx] = v;
    }

    // softmax(solver_params) — uniform, cheap
    float p0 = solver[0], p1 = solver[1], p2 = solver[2];
    float pm = fmaxf(p0, fmaxf(p1, p2));
    float e0 = expf(p0 - pm), e1 = expf(p1 - pm), e2 = expf(p2 - pm);
    float inv = 1.f / (e0 + e1 + e2);
    float w0 = e0 * inv, w1 = e1 * inv, w2 = e2 * inv;

    __syncthreads();

    const float gmax = fmaxf(fmaxf(s_wmax[0], s_wmax[1]), fmaxf(s_wmax[2], s_wmax[3]));
    const float inv_max = 1.f / (gmax + 1e-8f);
    const float k0 = -25.132741228718345f * w0;   // w0 * (-8*pi*G/c^4)
    const float potscale = 2.f * w1 * inv_max;    // folds mass normalization

    // stage 2: pre-smooth metric over 18x18 region (origin at tile-1)
    for (int idx = tid; idx < 18 * 18; idx += 256) {
        int ly = idx / 18, lx = idx % 18;
        int gy = tile_y + ly - 1, gx = tile_x + lx - 1;
        if ((unsigned)gy >= GH || (unsigned)gx >= GW) {
            #pragma unroll
            for (int cp = 0; cp < 5; cp++)
                s_met2[cp][ly][lx] = make_float2(0.f, 0.f);  // zero pad
            continue;
        }
        const int cy = ly + 3, cx = lx + 3;
        float m = s_mass[cy][cx];
        // 7x7 Green conv, symmetric-paired: w(dy,dx) == w(-dy,-dx)
        float pot = 0.f;
        #pragma unroll
        for (int dy = 0; dy <= 3; dy++) {
            #pragma unroll
            for (int dx = -3; dx <= 3; dx++) {
                if (dy == 0 && dx <= 0) continue;
                const float wgt = -0.15915494309189535f /
                                  __builtin_sqrtf((float)(dy * dy + dx * dx));
                pot += wgt * (s_mass[cy + dy][cx + dx] + s_mass[cy - dy][cx - dx]);
            }
        }
        float potterm = potscale * pot;
        // LUT lerp (float2 pairs)
        float x = m * 256.f;
        int i0 = (int)x;
        i0 = i0 < 255 ? i0 : 255;
        float f = x - (float)i0;
        const float2* l0 = s_lut2 + i0 * 5;
        const float2* mi2 = (const float2*)(minit + ((size_t)(b * GH + gy) * GW + gx) * NC);
        #pragma unroll
        for (int cp = 0; cp < 5; cp++) {
            float2 t0 = l0[cp], t1 = l0[5 + cp];
            float2 mi = mi2[cp];
            float2 v;
            v.x = fmaf(k0, fmaf(f, t1.x - t0.x, t0.x), mi.x);
            v.y = fmaf(k0, fmaf(f, t1.y - t0.y, t0.y), mi.y);
            if (cp == 2) v.x += potterm;              // c4
            if (cp == 3) v.y += potterm;              // c7
            if (cp == 0) v.x = fminf(v.x, -0.1f);     // c0
            if (cp == 2) v.x = fmaxf(v.x, 0.1f);      // c4
            if (cp == 3) v.y = fmaxf(v.y, 0.1f);      // c7
            if (cp == 4) v.y = fmaxf(v.y, 0.1f);      // c9
            s_met2[cp][ly][lx] = v;
        }
    }
    __syncthreads();

    // stage 3: 3x3 Gaussian, select by w2>0.1, float2 stores
    const int ly = ty + 1, lx = tx + 1;
    const int gy = tile_y + ty, gx = tile_x + tx;
    float2* outp2 = (float2*)(out + ((size_t)(b * GH + gy) * GW + gx) * NC);
    const float g0 = 0.274068619f, g1 = 0.451862761f;
    if (w2 > 0.1f) {
        #pragma unroll
        for (int cp = 0; cp < 5; cp++) {
            float2 m00 = s_met2[cp][ly - 1][lx - 1], m01 = s_met2[cp][ly - 1][lx], m02 = s_met2[cp][ly - 1][lx + 1];
            float2 m10 = s_met2[cp][ly][lx - 1],     m11 = s_met2[cp][ly][lx],     m12 = s_met2[cp][ly][lx + 1];
            float2 m20 = s_met2[cp][ly + 1][lx - 1], m21 = s_met2[cp][ly + 1][lx], m22 = s_met2[cp][ly + 1][lx + 1];
            float2 v;
            float r0 = fmaf(g0, m00.x, fmaf(g1, m01.x, g0 * m02.x));
            float r1 = fmaf(g0, m10.x, fmaf(g1, m11.x, g0 * m12.x));
            float r2 = fmaf(g0, m20.x, fmaf(g1, m21.x, g0 * m22.x));
            v.x = fmaf(g0, r0, fmaf(g1, r1, g0 * r2));
            r0 = fmaf(g0, m00.y, fmaf(g1, m01.y, g0 * m02.y));
            r1 = fmaf(g0, m10.y, fmaf(g1, m11.y, g0 * m12.y));
            r2 = fmaf(g0, m20.y, fmaf(g1, m21.y, g0 * m22.y));
            v.y = fmaf(g0, r0, fmaf(g1, r1, g0 * r2));
            outp2[cp] = v;
        }
    } else {
        #pragma unroll
        for (int cp = 0; cp < 5; cp++) outp2[cp] = s_met2[cp][ly][lx];
    }
}

extern "C" void kernel_launch(void* const* d_in, const int* in_sizes, int n_in,
                              void* d_out, int out_size, void* d_ws, size_t ws_size,
                              hipStream_t stream) {
    const float* mass   = (const float*)d_in[0];
    const float* vel    = (const float*)d_in[1];
    const float* minit  = (const float*)d_in[2];
    const float* e_w1   = (const float*)d_in[3];
    const float* e_b1   = (const float*)d_in[4];
    const float* e_w2   = (const float*)d_in[5];
    const float* e_b2   = (const float*)d_in[6];
    const float* m_w1   = (const float*)d_in[7];
    const float* m_b1   = (const float*)d_in[8];
    const float* m_w2   = (const float*)d_in[9];
    const float* m_b2   = (const float*)d_in[10];
    const float* s_w1   = (const float*)d_in[11];
    const float* s_b1   = (const float*)d_in[12];
    const float* s_w2   = (const float*)d_in[13];
    const float* s_b2   = (const float*)d_in[14];
    const float* solver = (const float*)d_in[15];
    float* ws  = (float*)d_ws;
    float* out = (float*)d_out;

    k_pre<<<770, 256, 0, stream>>>(mass, vel, e_w1, e_b1, e_w2, e_b2,
                                   m_w1, m_b1, m_w2, m_b2,
                                   s_w1, s_b1, s_w2, s_b2, ws);
    dim3 grid(GW / 16, GH / 16, 8);
    k_main<<<grid, 256, 0, stream>>>(mass, minit, solver, ws, out);
}